// Round 7
// baseline (280.783 us; speedup 1.0000x reference)
//
#include <hip/hip_runtime.h>
#include <hip/hip_bf16.h>

#define BB 4
#define NH 8
#define HD 64
#define CC 512
#define LL 2048
#define KK 1536   // C*3, K index = t*512 + ci
#define LPAD 2050 // padded rows of xT: row 0 and row 2049 are zeros

typedef float f32x4 __attribute__((ext_vector_type(4)));
typedef short bf16x8 __attribute__((ext_vector_type(8)));

static __device__ __forceinline__ ushort f2bf(float f) {
  union { float f; unsigned u; } v; v.f = f;
  unsigned r = v.u + 0x7fffu + ((v.u >> 16) & 1u);   // RNE
  return (ushort)(r >> 16);
}
static __device__ __forceinline__ void gload16(const ushort* g, ushort* l) {
  __builtin_amdgcn_global_load_lds((const __attribute__((address_space(1))) void*)g,
                                   (__attribute__((address_space(3))) void*)l, 16, 0, 0);
}

// ---------------------------------------------------------------------------
// Weight prep: W[co][ci][t] fp32 -> W'[co][t*512+ci] bf16, for all 4 convs.
// ---------------------------------------------------------------------------
__global__ void prep_w(const float* __restrict__ w0, const float* __restrict__ w1,
                       const float* __restrict__ w2, const float* __restrict__ w3,
                       ushort* __restrict__ out)
{
  int i = blockIdx.x * 256 + threadIdx.x;
  const int per = CC * KK;
  if (i >= 4 * per) return;
  int cidx = i / per;
  int rem  = i - cidx * per;
  int co   = rem / KK;
  int kk   = rem - co * KK;
  int t = kk >> 9, ci = kk & 511;
  const float* w = (cidx == 0) ? w0 : (cidx == 1) ? w1 : (cidx == 2) ? w2 : w3;
  out[i] = f2bf(w[((size_t)co * CC + ci) * 3 + t]);
}

// ---------------------------------------------------------------------------
// Transpose+cast body: xb[c][l] fp32 -> ob[l+1][c] bf16, zero halo rows.
// ---------------------------------------------------------------------------
__device__ __forceinline__ void transpose_body(const float* __restrict__ xb,
                                               ushort* __restrict__ ob)
{
  const int c0 = blockIdx.y * 64;
  const int l0 = blockIdx.x * 64;
  const int tid = threadIdx.x;
  __shared__ ushort T[64 * 72];
  {
    const int rr = tid >> 4;      // 0..15
    const int f4 = tid & 15;      // 0..15
#pragma unroll
    for (int it = 0; it < 4; ++it) {
      const int cc = rr + it * 16;
      ushort s[4];
      float4 vv = *(const float4*)(xb + (size_t)(c0 + cc) * LL + l0 + f4 * 4);
      s[0] = f2bf(vv.x); s[1] = f2bf(vv.y); s[2] = f2bf(vv.z); s[3] = f2bf(vv.w);
      *(ushort4*)&T[cc * 72 + f4 * 4] = *(ushort4*)s;
    }
  }
  __syncthreads();
  {
    const int lr = tid >> 3;     // 0..31
    const int ch = tid & 7;      // 0..7
#pragma unroll
    for (int it = 0; it < 2; ++it) {
      const int ll = lr + it * 32;
      ushort tmp[8];
#pragma unroll
      for (int e = 0; e < 8; ++e) tmp[e] = T[(ch * 8 + e) * 72 + ll];
      *(uint4*)(ob + (size_t)(l0 + ll + 1) * CC + c0 + ch * 8) = *(uint4*)tmp;
    }
  }
  if (blockIdx.x == 0 && tid < 8) {
    uint4 z4 = make_uint4(0, 0, 0, 0);
    *(uint4*)(ob + c0 + tid * 8) = z4;
  }
  if (blockIdx.x == (LL / 64 - 1) && tid >= 248) {
    uint4 z4 = make_uint4(0, 0, 0, 0);
    *(uint4*)(ob + (size_t)(LPAD - 1) * CC + c0 + (tid - 248) * 8) = z4;
  }
}

__global__ __launch_bounds__(256, 2)
void transpose_k(const float* __restrict__ in, ushort* __restrict__ outT)
{
  const int b = blockIdx.z;
  transpose_body(in + (size_t)b * CC * LL, outT + (size_t)b * (LPAD * CC));
}

__global__ __launch_bounds__(256, 2)
void transpose3_k(const float* __restrict__ q, const float* __restrict__ k,
                  const float* __restrict__ v, ushort* __restrict__ xq,
                  ushort* __restrict__ xk, ushort* __restrict__ xv)
{
  const int z = blockIdx.z;
  const int b = z & 3, var = z >> 2;
  const float* in = (var == 0) ? q : (var == 1) ? k : v;
  ushort* out = (var == 0) ? xq : (var == 1) ? xk : xv;
  transpose_body(in + (size_t)b * CC * LL, out + (size_t)b * (LPAD * CC));
}

// ---------------------------------------------------------------------------
// conv1d(k=3,same) as implicit GEMM.  Tile M=128(co) x N=128(l), BK=32,
// LDS DOUBLE-BUFFERED (2x16 KB): single barrier per K-iter, prefetch of
// iter t+1 issued right after the barrier (overlaps compute of iter t).
// Staging = 4x global_load_lds(16B)/thread, XOR chunk swizzle (4 chunks/row,
// s(row) = (row>>1)&3) -> frag ds_read_b128 lands 2-way max.
// mode 0: heads [b][h][x][d] bf16 (q,k) | 1: heads-T [b][h][d][x] bf16 (v)
// mode 2: [b][co][l] fp32 (final fc)
// ---------------------------------------------------------------------------
__device__ __forceinline__ void conv_body(const ushort* __restrict__ xb,
                                          const ushort* __restrict__ Wt,
                                          const float* __restrict__ bias,
                                          void* __restrict__ outp, int mode, int b)
{
  const int co0 = blockIdx.y * 128;
  const int l0  = blockIdx.x * 128;
  const int tid = threadIdx.x;
  const int lane = tid & 63;
  const int w    = tid >> 6;
  const int col  = lane & 15, quad = lane >> 4;

  __shared__ ushort Asl[2][128 * 32];   // 8 KB per buffer
  __shared__ ushort Bsl[2][128 * 32];   // total 32 KB

  const int sr = tid >> 2;                    // 0..63
  const int g8 = ((tid & 3) ^ ((sr >> 1) & 3)) * 8;
  const ushort* ag = Wt + (size_t)(co0 + sr) * KK + g8;
  const ushort* bg = xb + (size_t)(l0 + sr) * CC + g8;

  f32x4 acc[4][4] = {};
  const int wm = (w & 1) * 64;
  const int wn = (w >> 1) * 64;
  const int cs = (col >> 1) & 3;              // frag-read chunk swizzle

  // prefetch k0=0 into buf 0
  gload16(ag, &Asl[0][tid * 8]);
  gload16(ag + (size_t)64 * KK, &Asl[0][2048 + tid * 8]);
  gload16(bg, &Bsl[0][tid * 8]);
  gload16(bg + (size_t)64 * CC, &Bsl[0][2048 + tid * 8]);

  for (int k0 = 0; k0 < KK; k0 += 32) {
    const int cur = (k0 >> 5) & 1;
    __syncthreads();   // drains prefetch into buf[cur]; fences buf[1-cur] readers
    if (k0 + 32 < KK) {
      ushort* a2 = &Asl[1 - cur][tid * 8];
      ushort* b2 = &Bsl[1 - cur][tid * 8];
      gload16(ag + k0 + 32, a2);
      gload16(ag + (size_t)64 * KK + k0 + 32, a2 + 2048);
      gload16(bg + k0 + 32, b2);
      gload16(bg + (size_t)64 * CC + k0 + 32, b2 + 2048);
    }
    bf16x8 af[4], bfr[4];
#pragma unroll
    for (int i = 0; i < 4; ++i)
      af[i] = *(const bf16x8*)&Asl[cur][(wm + i * 16 + col) * 32 + ((quad ^ cs) * 8)];
#pragma unroll
    for (int j = 0; j < 4; ++j)
      bfr[j] = *(const bf16x8*)&Bsl[cur][(wn + j * 16 + col) * 32 + ((quad ^ cs) * 8)];
#pragma unroll
    for (int i = 0; i < 4; ++i)
#pragma unroll
      for (int j = 0; j < 4; ++j)
        acc[i][j] = __builtin_amdgcn_mfma_f32_16x16x32_bf16(af[i], bfr[j], acc[i][j], 0, 0, 0);
  }

  // epilogue: C/D layout row = quad*4+r (co), col = lane&15 (l)
#pragma unroll
  for (int i = 0; i < 4; ++i) {
#pragma unroll
    for (int r = 0; r < 4; ++r) {
      const int co = co0 + wm + i * 16 + quad * 4 + r;
      const float bi = bias[co];
#pragma unroll
      for (int j = 0; j < 4; ++j) {
        const int l = l0 + wn + j * 16 + col;
        const float y = acc[i][j][r] + bi;
        if (mode == 0) {
          const int xx = (co << 2) + (l >> 9);
          const int hh = (l >> 6) & 7;
          const int dd = l & 63;
          ((ushort*)outp)[((size_t)(b * NH + hh) * LL + xx) * HD + dd] = f2bf(y);
        } else if (mode == 1) {
          const int xx = (co << 2) + (l >> 9);
          const int hh = (l >> 6) & 7;
          const int dd = l & 63;
          ((ushort*)outp)[((size_t)(b * NH + hh) * HD + dd) * LL + xx] = f2bf(y);
        } else {
          ((float*)outp)[(size_t)(b * CC + co) * LL + l] = y;
        }
      }
    }
  }
}

__global__ __launch_bounds__(256, 3)
void conv_k(const ushort* __restrict__ xT, const ushort* __restrict__ Wt,
            const float* __restrict__ bias, void* __restrict__ outp, int mode)
{
  const int b = blockIdx.z;
  conv_body(xT + (size_t)b * (LPAD * CC), Wt, bias, outp, mode, b);
}

__global__ __launch_bounds__(256, 3)
void conv3_k(const ushort* __restrict__ xq, const ushort* __restrict__ xk,
             const ushort* __restrict__ xv, const ushort* __restrict__ Wt,
             const float* __restrict__ b0, const float* __restrict__ b1,
             const float* __restrict__ b2, ushort* __restrict__ o0,
             ushort* __restrict__ o1, ushort* __restrict__ o2)
{
  const int z = blockIdx.z;
  const int b = z & 3, var = z >> 2;
  const ushort* xT = (var == 0) ? xq : (var == 1) ? xk : xv;
  const float* bias = (var == 0) ? b0 : (var == 1) ? b1 : b2;
  ushort* outp = (var == 0) ? o0 : (var == 1) ? o1 : o2;
  conv_body(xT + (size_t)b * (LPAD * CC), Wt + (size_t)var * CC * KK, bias, outp,
            (var == 2) ? 1 : 0, b);
}

// ---------------------------------------------------------------------------
// Attention v6: as v5 (4 waves x 32 Q-rows, dbuf LDS K/V staging, 1 barrier
// per y-tile, direct transposed output) BUT computes S^T = K Q^T (operand
// swap — free) so each lane's 4 accumulator regs are 4 CONSECUTIVE y values
// of P[x][y]: the 32 conflicted ds_write_b16 of the C->A round trip become
// 8 aligned ds_write_b64 (packed bf16x4).  ap reads / PV / ones-MFMA denom /
// epilogue unchanged.
// ---------------------------------------------------------------------------
__global__ __launch_bounds__(256, 2)
void attn_k(const ushort* __restrict__ qh, const ushort* __restrict__ kh,
            const ushort* __restrict__ vt, ushort* __restrict__ obT)
{
  const int id   = blockIdx.x;
  const int xcd  = id & 7;
  const int slot = id >> 3;          // 0..63
  const int bh   = xcd * 4 + (slot >> 4);
  const int x0   = (slot & 15) * 128;
  const int b = bh >> 3, h = bh & 7;
  const int tid = threadIdx.x, lane = tid & 63, wv = tid >> 6;
  const int col = lane & 15, quad = lane >> 4;
  const int wx = wv * 32;            // wave-private Q rows / P rows
  const int c7 = col & 7;

  __shared__ ushort Kv[2][8192];     // [buf][ K 64x64 | V^T 64x64 ]  32 KB
  __shared__ ushort Ps[128 * 88];    // 22.5 KB  (P[x][y], stride 88)

  const ushort* Qg = qh + (size_t)bh * (LL * HD);
  const ushort* Kg = kh + (size_t)bh * (LL * HD);
  const ushort* Vg = vt + (size_t)bh * (HD * LL);
  ushort* ob = obT + (size_t)b * (LPAD * CC);

  const int sr = tid >> 3;                 // 0..31
  const int g8 = ((tid & 7) ^ (sr & 7)) * 8;

  // Q fragments (lane&15 = x-row, k = quad*8+j) — valid as A or B operand
  bf16x8 aq[2][2];
#pragma unroll
  for (int i = 0; i < 2; ++i)
#pragma unroll
    for (int kk = 0; kk < 2; ++kk)
      aq[i][kk] = *(const bf16x8*)(Qg + (size_t)(x0 + wx + i * 16 + col) * HD + kk * 32 + quad * 8);

  const short one = (short)0x3F80;  // bf16 1.0
  const bf16x8 ones = {one, one, one, one, one, one, one, one};

  f32x4 oacc[2][4] = {};
  f32x4 dacc[2] = {};

  // prefetch y-tile 0 into buf 0
  {
    ushort* kb = &Kv[0][tid * 8];
    gload16(Kg + (size_t)sr * HD + g8, kb);
    gload16(Kg + (size_t)(32 + sr) * HD + g8, kb + 2048);
    gload16(Vg + (size_t)sr * LL + g8, kb + 4096);
    gload16(Vg + (size_t)(32 + sr) * LL + g8, kb + 6144);
  }

  for (int yt = 0; yt < 32; ++yt) {
    const int cur = yt & 1;
    __syncthreads();
    if (yt + 1 < 32) {
      const int y1 = (yt + 1) * 64;
      ushort* kb = &Kv[1 - cur][tid * 8];
      gload16(Kg + (size_t)(y1 + sr) * HD + g8, kb);
      gload16(Kg + (size_t)(y1 + 32 + sr) * HD + g8, kb + 2048);
      gload16(Vg + (size_t)sr * LL + y1 + g8, kb + 4096);
      gload16(Vg + (size_t)(32 + sr) * LL + y1 + g8, kb + 6144);
    }
    const ushort* Kb = &Kv[cur][0];
    const ushort* Vb = &Kv[cur][4096];

    // S^T = K Q^T : sacc[j][i] rows (quad*4+r) = y-local, cols = x-local
    f32x4 sacc[4][2] = {};
#pragma unroll
    for (int kk = 0; kk < 2; ++kk)
#pragma unroll
      for (int j = 0; j < 4; ++j) {
        bf16x8 bk = *(const bf16x8*)&Kb[(j * 16 + col) * 64 + (((kk * 4 + quad) ^ c7) * 8)];
        sacc[j][0] = __builtin_amdgcn_mfma_f32_16x16x32_bf16(bk, aq[0][kk], sacc[j][0], 0, 0, 0);
        sacc[j][1] = __builtin_amdgcn_mfma_f32_16x16x32_bf16(bk, aq[1][kk], sacc[j][1], 0, 0, 0);
      }
    // exp + pack 4 consecutive-y bf16 -> one ds_write_b64 per (j,i)
#pragma unroll
    for (int j = 0; j < 4; ++j)
#pragma unroll
      for (int i = 0; i < 2; ++i) {
        union { __hip_bfloat162 h[2]; uint2 u; } pk;
        pk.h[0] = __float22bfloat162_rn(make_float2(__expf(sacc[j][i][0] * 0.015625f),
                                                   __expf(sacc[j][i][1] * 0.015625f)));
        pk.h[1] = __float22bfloat162_rn(make_float2(__expf(sacc[j][i][2] * 0.015625f),
                                                   __expf(sacc[j][i][3] * 0.015625f)));
        *(uint2*)&Ps[(wx + i * 16 + col) * 88 + j * 16 + quad * 4] = pk.u;
      }
    // O += P V ; denom += P * ones   (ap = A-layout P, V^T rows d, k=y)
#pragma unroll
    for (int kk = 0; kk < 2; ++kk) {
      bf16x8 ap0 = *(const bf16x8*)&Ps[(wx + col) * 88 + kk * 32 + quad * 8];
      bf16x8 ap1 = *(const bf16x8*)&Ps[(wx + 16 + col) * 88 + kk * 32 + quad * 8];
      dacc[0] = __builtin_amdgcn_mfma_f32_16x16x32_bf16(ap0, ones, dacc[0], 0, 0, 0);
      dacc[1] = __builtin_amdgcn_mfma_f32_16x16x32_bf16(ap1, ones, dacc[1], 0, 0, 0);
#pragma unroll
      for (int j = 0; j < 4; ++j) {
        bf16x8 bv = *(const bf16x8*)&Vb[(j * 16 + col) * 64 + (((kk * 4 + quad) ^ c7) * 8)];
        oacc[0][j] = __builtin_amdgcn_mfma_f32_16x16x32_bf16(ap0, bv, oacc[0][j], 0, 0, 0);
        oacc[1][j] = __builtin_amdgcn_mfma_f32_16x16x32_bf16(ap1, bv, oacc[1][j], 0, 0, 0);
      }
    }
  }

  // normalize + scatter DIRECTLY to padded-transposed [b][l+1][c] bf16
#pragma unroll
  for (int i = 0; i < 2; ++i) {
#pragma unroll
    for (int r = 0; r < 4; ++r) {
      const int xg = x0 + wx + i * 16 + quad * 4 + r;
      const float inv = 1.f / dacc[i][r];
#pragma unroll
      for (int j = 0; j < 4; ++j) {
        const int d = j * 16 + col;
        const int flat = xg * 512 + h * 64 + d;
        const int c = flat >> 11, l = flat & 2047;
        ob[(size_t)(l + 1) * CC + c] = f2bf(oacc[i][j][r] * inv);
      }
    }
  }
  if ((slot & 15) == 0 && tid < 128) {
    const int row = tid >> 6;
    const int cc  = h * 64 + (tid & 63);
    ob[(size_t)(row ? (LPAD - 1) : 0) * CC + cc] = 0;
  }
}

// ---------------------------------------------------------------------------
extern "C" void kernel_launch(void* const* d_in, const int* in_sizes, int n_in,
                              void* d_out, int out_size, void* d_ws, size_t ws_size,
                              hipStream_t stream) {
  const float* q    = (const float*)d_in[0];
  const float* k    = (const float*)d_in[1];
  const float* v    = (const float*)d_in[2];
  const float* wq_w = (const float*)d_in[3];
  const float* wq_b = (const float*)d_in[4];
  const float* wk_w = (const float*)d_in[5];
  const float* wk_b = (const float*)d_in[6];
  const float* wv_w = (const float*)d_in[7];
  const float* wv_b = (const float*)d_in[8];
  const float* fc_w = (const float*)d_in[9];
  const float* fc_b = (const float*)d_in[10];

  char* ws = (char*)d_ws;
  const size_t WSZ = (size_t)CC * KK * sizeof(ushort);            // 1.5 MB per conv
  const size_t HSZ = (size_t)BB * NH * LL * HD * sizeof(ushort);  // 8.39 MB per head tensor
  const size_t XSZ = (size_t)BB * LPAD * CC * sizeof(ushort);     // 8.40 MB padded xT
  const size_t FUSED_NEED = 4 * WSZ + 3 * HSZ + 3 * XSZ;          // ~56.65 MB

  ushort* Wt = (ushort*)(ws);
  prep_w<<<(4 * CC * KK + 255) / 256, 256, 0, stream>>>(wq_w, wk_w, wv_w, fc_w, Wt);

  if (ws_size >= FUSED_NEED) {
    ushort* qh  = (ushort*)(ws + 4 * WSZ);
    ushort* kh  = (ushort*)(ws + 4 * WSZ + HSZ);
    ushort* vt  = (ushort*)(ws + 4 * WSZ + 2 * HSZ);
    ushort* xTq = (ushort*)(ws + 4 * WSZ + 3 * HSZ);
    ushort* xTk = (ushort*)(ws + 4 * WSZ + 3 * HSZ + XSZ);
    ushort* xTv = (ushort*)(ws + 4 * WSZ + 3 * HSZ + 2 * XSZ);
    ushort* obT = xTq;   // attn writes transposed output here (xTq dead after conv3)

    transpose3_k<<<dim3(32, 8, 12), 256, 0, stream>>>(q, k, v, xTq, xTk, xTv);
    conv3_k<<<dim3(16, 4, 12), 256, 0, stream>>>(xTq, xTk, xTv, Wt,
                                                 wq_b, wk_b, wv_b, qh, kh, vt);
    attn_k<<<512, 256, 0, stream>>>(qh, kh, vt, obT);
    conv_k<<<dim3(16, 4, 4), 256, 0, stream>>>(obT, Wt + 3 * CC * KK, fc_b,
                                               (float*)d_out, 2);
  } else {
    ushort* qh  = (ushort*)(ws + 4 * WSZ);
    ushort* kh  = (ushort*)(ws + 4 * WSZ + HSZ);
    ushort* vt  = (ushort*)(ws + 4 * WSZ + 2 * HSZ);
    ushort* xTb = (ushort*)(ws + 4 * WSZ + 3 * HSZ);
    ushort* obT = xTb;

    transpose_k<<<dim3(32, 8, 4), 256, 0, stream>>>(q, xTb);
    conv_k<<<dim3(16, 4, 4), 256, 0, stream>>>(xTb, Wt + 0 * CC * KK, wq_b, qh, 0);
    transpose_k<<<dim3(32, 8, 4), 256, 0, stream>>>(k, xTb);
    conv_k<<<dim3(16, 4, 4), 256, 0, stream>>>(xTb, Wt + 1 * CC * KK, wk_b, kh, 0);
    transpose_k<<<dim3(32, 8, 4), 256, 0, stream>>>(v, xTb);
    conv_k<<<dim3(16, 4, 4), 256, 0, stream>>>(xTb, Wt + 2 * CC * KK, wv_b, vt, 1);
    attn_k<<<512, 256, 0, stream>>>(qh, kh, vt, obT);
    conv_k<<<dim3(16, 4, 4), 256, 0, stream>>>(obT, Wt + 3 * CC * KK, fc_b,
                                               (float*)d_out, 2);
  }
}